// Round 6
// baseline (270.507 us; speedup 1.0000x reference)
//
#include <hip/hip_runtime.h>

// R31 — resubmit of R30 (GPU acquisition timeout; run-length theory untested).
// Evidence (R29 profile): harness fillBuffer sustains 6.4 TB/s writing 1 GiB
// linearly (cached stores, 10% occupancy); our kernel (~100us inferred) gets
// ~2.7 TB/s. NT vs cached was neutral -> cache policy isn't the limiter;
// write-run length is the standing suspect.
// Old: 2048 blocks x 4KB runs per t-plane (thousands of short DRAM streams).
// New: 512 blocks x 16KB runs per t-plane — 16 floats/thread as 4x float4 at
// wave-stride (each store 1KB wave-contiguous; block covers 16KB contiguous).
// Cached stores (match the 6.4 TB/s exemplar). Numerics identical to
// census-proven R25: acc += x; m = acc>=thr; sp = m?1:0; acc = m?0:acc;
// thr = fmaf(thr, 0.9f, 0.1f*|x|)  <- single rounding (matches XLA fusion).

#define TSTEPS 32
#define BDIM 32
#define FDIM 65536
#define TPB 256
#define FPT 16                    // floats per thread
#define CHUNK (TPB * FPT)         // 4096 floats = 16 KB per block per t-plane

typedef float floatx4 __attribute__((ext_vector_type(4)));

__global__ __launch_bounds__(256) void spike_fma_f32_wide_kernel(
    const float* __restrict__ x, float* __restrict__ out) {
    int w  = blockIdx.x;          // 0..511
    int b  = w >> 4;              // 16 chunks per batch row
    int c  = w & 15;
    int f0 = c * CHUNK + (int)threadIdx.x * 4;   // this thread's j=0 slot

    const float* xb  = x   + (size_t)b * FDIM + f0;
    float*       outb = out + (size_t)b * TSTEPS * FDIM + f0;

    float xs[4][4], acc[4][4], thr[4][4], ad[4][4];
#pragma unroll
    for (int j = 0; j < 4; ++j) {
        const floatx4 v = *reinterpret_cast<const floatx4*>(xb + j * 1024);
#pragma unroll
        for (int e = 0; e < 4; ++e) {
            xs[j][e]  = v[e];
            acc[j][e] = 0.0f;
            thr[j][e] = 0.5f;
            ad[j][e]  = 0.1f * fabsf(v[e]);    // one rounding
        }
    }

#pragma unroll
    for (int t = 0; t < TSTEPS; ++t) {
        floatx4 sp[4];
#pragma unroll
        for (int j = 0; j < 4; ++j) {
#pragma unroll
            for (int e = 0; e < 4; ++e) {
                acc[j][e] = acc[j][e] + xs[j][e];
                bool m    = acc[j][e] >= thr[j][e];
                sp[j][e]  = m ? 1.0f : 0.0f;
                acc[j][e] = m ? 0.0f : acc[j][e];
                thr[j][e] = __builtin_fmaf(thr[j][e], 0.9f, ad[j][e]); // fused
            }
        }
        float* ot = outb + (size_t)t * FDIM;
#pragma unroll
        for (int j = 0; j < 4; ++j)          // 4 back-to-back 1KB wave stores
            *reinterpret_cast<floatx4*>(ot + j * 1024) = sp[j];
    }
}

extern "C" void kernel_launch(void* const* d_in, const int* in_sizes, int n_in,
                              void* d_out, int out_size, void* d_ws, size_t ws_size,
                              hipStream_t stream) {
    (void)in_sizes; (void)n_in; (void)d_ws; (void)ws_size; (void)out_size;
    const float* x = (const float*)d_in[0];
    float* out     = (float*)d_out;
    const int nblocks = BDIM * (FDIM / CHUNK);   // 32 * 16 = 512
    spike_fma_f32_wide_kernel<<<nblocks, TPB, 0, stream>>>(x, out);
}